// Round 1
// baseline (90299.182 us; speedup 1.0000x reference)
//
#include <hip/hip_runtime.h>
#include <hip/hip_cooperative_groups.h>

namespace cg = cooperative_groups;

#define T_ 1024
#define S_ 1024
#define H_ 2048
#define A_ 128
#define NB 256      // blocks (1 per CU)
#define BS 512      // threads per block (8 waves)
#define WPB 8       // waves per block
#define JPB 8       // h elements owned per block (H / NB)

__device__ __forceinline__ float sigmf(float v) {
    return 1.0f / (1.0f + __expf(-v));
}

// dot of row w[0:K) with vector v[0:K) distributed over 64 lanes, float4 loads.
__device__ __forceinline__ float dot_row(const float* __restrict__ w,
                                         const float* __restrict__ v,
                                         int K, int lane) {
    float a = 0.0f;
#pragma unroll 4
    for (int c = lane * 4; c < K; c += 256) {
        const float4 wv = *reinterpret_cast<const float4*>(w + c);
        const float4 vv = *reinterpret_cast<const float4*>(v + c);
        a = fmaf(wv.x, vv.x, a);
        a = fmaf(wv.y, vv.y, a);
        a = fmaf(wv.z, vv.z, a);
        a = fmaf(wv.w, vv.w, a);
    }
    return a;
}

__device__ __forceinline__ float wave_reduce(float a) {
#pragma unroll
    for (int off = 1; off < 64; off <<= 1) a += __shfl_xor(a, off);
    return a;
}

__global__ __launch_bounds__(BS, 1) void lstm_coop(
    const float* __restrict__ x,
    const float* __restrict__ Wih1, const float* __restrict__ Whh1,
    const float* __restrict__ bih1, const float* __restrict__ bhh1,
    const float* __restrict__ Wih2, const float* __restrict__ Whh2,
    const float* __restrict__ bih2, const float* __restrict__ bhh2,
    const float* __restrict__ Wlin, const float* __restrict__ blin,
    float* __restrict__ out, float* __restrict__ ws)
{
    cg::grid_group grid = cg::this_grid();

    // staging buffer for the two input vectors of the active phase
    __shared__ float sv[2 * H_];   // 16 KB

    const int b    = blockIdx.x;
    const int tid  = threadIdx.x;
    const int wave = tid >> 6;
    const int lane = tid & 63;
    const int j    = b * JPB + wave;   // the h-index this wave owns

    // ws layout: h1[2][H], h2[2][H] (double-buffered hidden states)
    float* h1buf[2] = { ws,          ws + H_ };
    float* h2buf[2] = { ws + 2 * H_, ws + 3 * H_ };

    // zero-init initial hidden state (buffer 0)
    if (tid < JPB) {
        h1buf[0][b * JPB + tid] = 0.0f;
        h2buf[0][b * JPB + tid] = 0.0f;
    }

    // hoist biases: row indices are fixed per wave
    float bias1[4], bias2[4];
#pragma unroll
    for (int g = 0; g < 4; ++g) {
        const int r = g * H_ + j;
        bias1[g] = bih1[r] + bhh1[r];
        bias2[g] = bih2[r] + bhh2[r];
    }

    grid.sync();

    float c1 = 0.0f, c2 = 0.0f;   // cell states, replicated across lanes

    for (int t = 0; t < T_; ++t) {
        const int p = t & 1;       // read buffer
        const int q = p ^ 1;       // write buffer

        // ---------------- phase A: layer-1 cell ----------------
        {
            const float* xt  = x + (size_t)t * S_;
            const float* h1p = h1buf[p];
            // stage x_t and h1_prev into LDS
            for (int i2 = tid; i2 < S_ / 4; i2 += BS)
                reinterpret_cast<float4*>(sv)[i2] =
                    reinterpret_cast<const float4*>(xt)[i2];
            for (int i2 = tid; i2 < H_ / 4; i2 += BS)
                reinterpret_cast<float4*>(sv + S_)[i2] =
                    reinterpret_cast<const float4*>(h1p)[i2];
            __syncthreads();

            float g4[4];
#pragma unroll
            for (int g = 0; g < 4; ++g) {
                const int r = g * H_ + j;
                float a = dot_row(Wih1 + (size_t)r * S_, sv,      S_, lane);
                a      += dot_row(Whh1 + (size_t)r * H_, sv + S_, H_, lane);
                g4[g] = wave_reduce(a) + bias1[g];
            }
            const float ig = sigmf(g4[0]);
            const float fg = sigmf(g4[1]);
            const float gg = tanhf(g4[2]);
            const float og = sigmf(g4[3]);
            c1 = fg * c1 + ig * gg;
            const float h1n = og * tanhf(c1);
            if (lane == 0) h1buf[q][j] = h1n;
        }
        grid.sync();

        // ---------------- phase B: layer-2 cell ----------------
        {
            const float* h1n_all = h1buf[q];
            const float* h2p     = h2buf[p];
            for (int i2 = tid; i2 < H_ / 4; i2 += BS)
                reinterpret_cast<float4*>(sv)[i2] =
                    reinterpret_cast<const float4*>(h1n_all)[i2];
            for (int i2 = tid; i2 < H_ / 4; i2 += BS)
                reinterpret_cast<float4*>(sv + H_)[i2] =
                    reinterpret_cast<const float4*>(h2p)[i2];
            __syncthreads();

            float g4[4];
#pragma unroll
            for (int g = 0; g < 4; ++g) {
                const int r = g * H_ + j;
                float a = dot_row(Wih2 + (size_t)r * H_, sv,      H_, lane);
                a      += dot_row(Whh2 + (size_t)r * H_, sv + H_, H_, lane);
                g4[g] = wave_reduce(a) + bias2[g];
            }
            const float ig = sigmf(g4[0]);
            const float fg = sigmf(g4[1]);
            const float gg = tanhf(g4[2]);
            const float og = sigmf(g4[3]);
            c2 = fg * c2 + ig * gg;
            const float h2n = og * tanhf(c2);
            if (lane == 0) h2buf[q][j] = h2n;
        }
        grid.sync();
    }

    // ---------------- linear head on final h2 ----------------
    // after t = T-1, write buffer was q = ((T-1)&1)^1 = 0 = T_&1
    const float* hf = h2buf[T_ & 1];
    if (b < A_ / WPB) {                 // 16 blocks x 8 waves = 128 rows
        const int r = b * WPB + wave;
        float a = dot_row(Wlin + (size_t)r * H_, hf, H_, lane);
        a = wave_reduce(a);
        if (lane == 0) out[r] = a + blin[r];
    }
}

extern "C" void kernel_launch(void* const* d_in, const int* in_sizes, int n_in,
                              void* d_out, int out_size, void* d_ws, size_t ws_size,
                              hipStream_t stream) {
    const float* x    = (const float*)d_in[0];
    const float* Wih1 = (const float*)d_in[1];
    const float* Whh1 = (const float*)d_in[2];
    const float* bih1 = (const float*)d_in[3];
    const float* bhh1 = (const float*)d_in[4];
    const float* Wih2 = (const float*)d_in[5];
    const float* Whh2 = (const float*)d_in[6];
    const float* bih2 = (const float*)d_in[7];
    const float* bhh2 = (const float*)d_in[8];
    const float* Wlin = (const float*)d_in[9];
    const float* blin = (const float*)d_in[10];
    float* out = (float*)d_out;
    float* wsf = (float*)d_ws;

    void* args[] = {
        (void*)&x,
        (void*)&Wih1, (void*)&Whh1, (void*)&bih1, (void*)&bhh1,
        (void*)&Wih2, (void*)&Whh2, (void*)&bih2, (void*)&bhh2,
        (void*)&Wlin, (void*)&blin,
        (void*)&out, (void*)&wsf
    };
    hipLaunchCooperativeKernel((void*)lstm_coop, dim3(NB), dim3(BS),
                               args, 0, stream);
}

// Round 2
// 86743.365 us; speedup vs baseline: 1.0410x; 1.0410x over previous
//
#include <hip/hip_runtime.h>
#include <hip/hip_cooperative_groups.h>

namespace cg = cooperative_groups;

#define T_ 1024
#define S_ 1024
#define H_ 2048
#define A_ 128
#define NB 256      // blocks (1 per CU)

// ---------------- bf16 main kernel config ----------------
#define BSM 1024    // threads per block (16 waves)
#define WPB 16      // waves per block
#define JPB 8       // h elements owned per block (H / NB)

__device__ __forceinline__ float sigmf(float v) {
    return 1.0f / (1.0f + __expf(-v));
}

__device__ __forceinline__ float wave_reduce(float a) {
#pragma unroll
    for (int off = 1; off < 64; off <<= 1) a += __shfl_xor(a, off);
    return a;
}

// unpack 8 bf16 (as uint4) and fma against 8 fp32 from LDS
__device__ __forceinline__ void acc8(float& a, const uint4 w,
                                     const float* __restrict__ v) {
    const float4 v0 = *reinterpret_cast<const float4*>(v);
    const float4 v1 = *reinterpret_cast<const float4*>(v + 4);
    a = fmaf(__uint_as_float(w.x << 16),          v0.x, a);
    a = fmaf(__uint_as_float(w.x & 0xffff0000u),  v0.y, a);
    a = fmaf(__uint_as_float(w.y << 16),          v0.z, a);
    a = fmaf(__uint_as_float(w.y & 0xffff0000u),  v0.w, a);
    a = fmaf(__uint_as_float(w.z << 16),          v1.x, a);
    a = fmaf(__uint_as_float(w.z & 0xffff0000u),  v1.y, a);
    a = fmaf(__uint_as_float(w.w << 16),          v1.z, a);
    a = fmaf(__uint_as_float(w.w & 0xffff0000u),  v1.w, a);
}

// ---------------- fp32 -> bf16 (RNE) conversion ----------------
__global__ void cvt_bf16(const float* __restrict__ src,
                         ushort* __restrict__ dst, int n4) {
    int i = blockIdx.x * blockDim.x + threadIdx.x;
    const int stride = gridDim.x * blockDim.x;
    for (; i < n4; i += stride) {
        const uint4 u = reinterpret_cast<const uint4*>(src)[i];
        ushort4 o;
        uint a;
        a = u.x; o.x = (ushort)((a + 0x7fffu + ((a >> 16) & 1u)) >> 16);
        a = u.y; o.y = (ushort)((a + 0x7fffu + ((a >> 16) & 1u)) >> 16);
        a = u.z; o.z = (ushort)((a + 0x7fffu + ((a >> 16) & 1u)) >> 16);
        a = u.w; o.w = (ushort)((a + 0x7fffu + ((a >> 16) & 1u)) >> 16);
        reinterpret_cast<ushort4*>(dst)[i] = o;
    }
}

// ---------------- bf16-weight persistent LSTM ----------------
__global__ __launch_bounds__(BSM, 4) void lstm_bf16(
    const float* __restrict__ x,
    const ushort* __restrict__ W1i, const ushort* __restrict__ W1h,
    const ushort* __restrict__ W2i, const ushort* __restrict__ W2h,
    const float* __restrict__ bih1, const float* __restrict__ bhh1,
    const float* __restrict__ bih2, const float* __restrict__ bhh2,
    const float* __restrict__ Wlin, const float* __restrict__ blin,
    float* __restrict__ out, float* __restrict__ hws)
{
    cg::grid_group grid = cg::this_grid();

    __shared__ float sv[2 * H_];        // 16 KB vector staging
    __shared__ float sg[JPB][4];        // gate exchange

    const int b    = blockIdx.x;
    const int tid  = threadIdx.x;
    const int w    = tid >> 6;
    const int lane = tid & 63;
    const int jl   = w >> 1;            // local h index 0..7
    const int j    = b * JPB + jl;      // global h index
    const int g0   = (w & 1) * 2;       // this wave's first gate (0 or 2)
    const int rA   = g0 * H_ + j;       // gate rows
    const int rB   = rA + H_;

    float* h1buf[2] = { hws,          hws + H_ };
    float* h2buf[2] = { hws + 2 * H_, hws + 3 * H_ };

    if (tid < JPB) {
        h1buf[0][b * JPB + tid] = 0.0f;
        h2buf[0][b * JPB + tid] = 0.0f;
    }

    // biases folded into this wave's two gate rows
    const float b1A = bih1[rA] + bhh1[rA], b1B = bih1[rB] + bhh1[rB];
    const float b2A = bih2[rA] + bhh2[rA], b2B = bih2[rB] + bhh2[rB];

    const ushort* p1iA = W1i + (size_t)rA * S_;
    const ushort* p1iB = W1i + (size_t)rB * S_;
    const ushort* p1hA = W1h + (size_t)rA * H_;
    const ushort* p1hB = W1h + (size_t)rB * H_;
    const ushort* p2iA = W2i + (size_t)rA * H_;
    const ushort* p2iB = W2i + (size_t)rB * H_;
    const ushort* p2hA = W2h + (size_t)rA * H_;
    const ushort* p2hB = W2h + (size_t)rB * H_;

    grid.sync();

    float c1 = 0.0f, c2 = 0.0f;   // cell state (valid on even waves)

    for (int t = 0; t < T_; ++t) {
        const int p = t & 1;
        const int q = p ^ 1;

        // ---------------- layer 1 ----------------
        {
            const float* xt  = x + (size_t)t * S_;
            const float* h1p = h1buf[p];
            for (int i = tid; i < S_ / 4; i += BSM)
                reinterpret_cast<float4*>(sv)[i] =
                    reinterpret_cast<const float4*>(xt)[i];
            for (int i = tid; i < H_ / 4; i += BSM)
                reinterpret_cast<float4*>(sv + S_)[i] =
                    reinterpret_cast<const float4*>(h1p)[i];
            __syncthreads();

            uint4 wiA[2], wiB[2], whA[4], whB[4];
#pragma unroll
            for (int i = 0; i < 2; ++i) {
                const int o = i * 512 + lane * 8;
                wiA[i] = *reinterpret_cast<const uint4*>(p1iA + o);
                wiB[i] = *reinterpret_cast<const uint4*>(p1iB + o);
            }
#pragma unroll
            for (int i = 0; i < 4; ++i) {
                const int o = i * 512 + lane * 8;
                whA[i] = *reinterpret_cast<const uint4*>(p1hA + o);
                whB[i] = *reinterpret_cast<const uint4*>(p1hB + o);
            }
            float a0 = 0.0f, a1 = 0.0f;
#pragma unroll
            for (int i = 0; i < 2; ++i) {
                const int o = i * 512 + lane * 8;
                acc8(a0, wiA[i], sv + o);
                acc8(a1, wiB[i], sv + o);
            }
#pragma unroll
            for (int i = 0; i < 4; ++i) {
                const int o = i * 512 + lane * 8;
                acc8(a0, whA[i], sv + S_ + o);
                acc8(a1, whB[i], sv + S_ + o);
            }
            a0 = wave_reduce(a0);
            a1 = wave_reduce(a1);
            if (lane == 0) {
                sg[jl][g0]     = a0 + b1A;
                sg[jl][g0 + 1] = a1 + b1B;
            }
            __syncthreads();
            if ((w & 1) == 0) {         // even wave owns cell state for j
                const float ig = sigmf(sg[jl][0]);
                const float fg = sigmf(sg[jl][1]);
                const float gg = tanhf(sg[jl][2]);
                const float og = sigmf(sg[jl][3]);
                c1 = fg * c1 + ig * gg;
                const float h1n = og * tanhf(c1);
                if (lane == 0) h1buf[q][j] = h1n;
            }
        }
        grid.sync();

        // ---------------- layer 2 ----------------
        {
            const float* h1n_all = h1buf[q];
            const float* h2p     = h2buf[p];
            for (int i = tid; i < H_ / 4; i += BSM)
                reinterpret_cast<float4*>(sv)[i] =
                    reinterpret_cast<const float4*>(h1n_all)[i];
            for (int i = tid; i < H_ / 4; i += BSM)
                reinterpret_cast<float4*>(sv + H_)[i] =
                    reinterpret_cast<const float4*>(h2p)[i];
            __syncthreads();

            uint4 wiA[4], wiB[4], whA[4], whB[4];
#pragma unroll
            for (int i = 0; i < 4; ++i) {
                const int o = i * 512 + lane * 8;
                wiA[i] = *reinterpret_cast<const uint4*>(p2iA + o);
                wiB[i] = *reinterpret_cast<const uint4*>(p2iB + o);
                whA[i] = *reinterpret_cast<const uint4*>(p2hA + o);
                whB[i] = *reinterpret_cast<const uint4*>(p2hB + o);
            }
            float a0 = 0.0f, a1 = 0.0f;
#pragma unroll
            for (int i = 0; i < 4; ++i) {
                const int o = i * 512 + lane * 8;
                acc8(a0, wiA[i], sv + o);
                acc8(a1, wiB[i], sv + o);
                acc8(a0, whA[i], sv + H_ + o);
                acc8(a1, whB[i], sv + H_ + o);
            }
            a0 = wave_reduce(a0);
            a1 = wave_reduce(a1);
            if (lane == 0) {
                sg[jl][g0]     = a0 + b2A;
                sg[jl][g0 + 1] = a1 + b2B;
            }
            __syncthreads();
            if ((w & 1) == 0) {
                const float ig = sigmf(sg[jl][0]);
                const float fg = sigmf(sg[jl][1]);
                const float gg = tanhf(sg[jl][2]);
                const float og = sigmf(sg[jl][3]);
                c2 = fg * c2 + ig * gg;
                const float h2n = og * tanhf(c2);
                if (lane == 0) h2buf[q][j] = h2n;
            }
        }
        grid.sync();
    }

    // ---------------- linear head on final h2 (buffer 0) ----------------
    const float* hf = h2buf[0];
    if (b < A_ / WPB) {                 // 8 blocks x 16 waves = 128 rows
        const int r = b * WPB + w;
        const float* wr = Wlin + (size_t)r * H_;
        float a = 0.0f;
#pragma unroll 4
        for (int c = lane * 4; c < H_; c += 256) {
            const float4 wv = *reinterpret_cast<const float4*>(wr + c);
            const float4 vv = *reinterpret_cast<const float4*>(hf + c);
            a = fmaf(wv.x, vv.x, a);
            a = fmaf(wv.y, vv.y, a);
            a = fmaf(wv.z, vv.z, a);
            a = fmaf(wv.w, vv.w, a);
        }
        a = wave_reduce(a);
        if (lane == 0) out[r] = a + blin[r];
    }
}

// ---------------- fp32 fallback (round-1 kernel) ----------------
#define BSF 512
#define WPBF 8

__device__ __forceinline__ float dot_row(const float* __restrict__ w,
                                         const float* __restrict__ v,
                                         int K, int lane) {
    float a = 0.0f;
#pragma unroll 4
    for (int c = lane * 4; c < K; c += 256) {
        const float4 wv = *reinterpret_cast<const float4*>(w + c);
        const float4 vv = *reinterpret_cast<const float4*>(v + c);
        a = fmaf(wv.x, vv.x, a);
        a = fmaf(wv.y, vv.y, a);
        a = fmaf(wv.z, vv.z, a);
        a = fmaf(wv.w, vv.w, a);
    }
    return a;
}

__global__ __launch_bounds__(BSF, 1) void lstm_coop(
    const float* __restrict__ x,
    const float* __restrict__ Wih1, const float* __restrict__ Whh1,
    const float* __restrict__ bih1, const float* __restrict__ bhh1,
    const float* __restrict__ Wih2, const float* __restrict__ Whh2,
    const float* __restrict__ bih2, const float* __restrict__ bhh2,
    const float* __restrict__ Wlin, const float* __restrict__ blin,
    float* __restrict__ out, float* __restrict__ ws)
{
    cg::grid_group grid = cg::this_grid();
    __shared__ float sv[2 * H_];
    const int b    = blockIdx.x;
    const int tid  = threadIdx.x;
    const int wave = tid >> 6;
    const int lane = tid & 63;
    const int j    = b * WPBF + wave;

    float* h1buf[2] = { ws,          ws + H_ };
    float* h2buf[2] = { ws + 2 * H_, ws + 3 * H_ };
    if (tid < WPBF) {
        h1buf[0][b * WPBF + tid] = 0.0f;
        h2buf[0][b * WPBF + tid] = 0.0f;
    }
    float bias1[4], bias2[4];
#pragma unroll
    for (int g = 0; g < 4; ++g) {
        const int r = g * H_ + j;
        bias1[g] = bih1[r] + bhh1[r];
        bias2[g] = bih2[r] + bhh2[r];
    }
    grid.sync();
    float c1 = 0.0f, c2 = 0.0f;
    for (int t = 0; t < T_; ++t) {
        const int p = t & 1, q = p ^ 1;
        {
            const float* xt  = x + (size_t)t * S_;
            const float* h1p = h1buf[p];
            for (int i2 = tid; i2 < S_ / 4; i2 += BSF)
                reinterpret_cast<float4*>(sv)[i2] = reinterpret_cast<const float4*>(xt)[i2];
            for (int i2 = tid; i2 < H_ / 4; i2 += BSF)
                reinterpret_cast<float4*>(sv + S_)[i2] = reinterpret_cast<const float4*>(h1p)[i2];
            __syncthreads();
            float g4[4];
#pragma unroll
            for (int g = 0; g < 4; ++g) {
                const int r = g * H_ + j;
                float a = dot_row(Wih1 + (size_t)r * S_, sv,      S_, lane);
                a      += dot_row(Whh1 + (size_t)r * H_, sv + S_, H_, lane);
                g4[g] = wave_reduce(a) + bias1[g];
            }
            const float ig = sigmf(g4[0]), fg = sigmf(g4[1]);
            const float gg = tanhf(g4[2]), og = sigmf(g4[3]);
            c1 = fg * c1 + ig * gg;
            if (lane == 0) h1buf[q][j] = og * tanhf(c1);
        }
        grid.sync();
        {
            const float* h1n_all = h1buf[q];
            const float* h2p     = h2buf[p];
            for (int i2 = tid; i2 < H_ / 4; i2 += BSF)
                reinterpret_cast<float4*>(sv)[i2] = reinterpret_cast<const float4*>(h1n_all)[i2];
            for (int i2 = tid; i2 < H_ / 4; i2 += BSF)
                reinterpret_cast<float4*>(sv + H_)[i2] = reinterpret_cast<const float4*>(h2p)[i2];
            __syncthreads();
            float g4[4];
#pragma unroll
            for (int g = 0; g < 4; ++g) {
                const int r = g * H_ + j;
                float a = dot_row(Wih2 + (size_t)r * H_, sv,      H_, lane);
                a      += dot_row(Whh2 + (size_t)r * H_, sv + H_, H_, lane);
                g4[g] = wave_reduce(a) + bias2[g];
            }
            const float ig = sigmf(g4[0]), fg = sigmf(g4[1]);
            const float gg = tanhf(g4[2]), og = sigmf(g4[3]);
            c2 = fg * c2 + ig * gg;
            if (lane == 0) h2buf[q][j] = og * tanhf(c2);
        }
        grid.sync();
    }
    const float* hf = h2buf[0];
    if (b < A_ / WPBF) {
        const int r = b * WPBF + wave;
        float a = dot_row(Wlin + (size_t)r * H_, hf, H_, lane);
        a = wave_reduce(a);
        if (lane == 0) out[r] = a + blin[r];
    }
}

extern "C" void kernel_launch(void* const* d_in, const int* in_sizes, int n_in,
                              void* d_out, int out_size, void* d_ws, size_t ws_size,
                              hipStream_t stream) {
    const float* x    = (const float*)d_in[0];
    const float* Wih1 = (const float*)d_in[1];
    const float* Whh1 = (const float*)d_in[2];
    const float* bih1 = (const float*)d_in[3];
    const float* bhh1 = (const float*)d_in[4];
    const float* Wih2 = (const float*)d_in[5];
    const float* Whh2 = (const float*)d_in[6];
    const float* bih2 = (const float*)d_in[7];
    const float* bhh2 = (const float*)d_in[8];
    const float* Wlin = (const float*)d_in[9];
    const float* blin = (const float*)d_in[10];
    float* out = (float*)d_out;
    float* wsf = (float*)d_ws;

    const size_t n1i = (size_t)4 * H_ * S_;   // 8,388,608
    const size_t nhh = (size_t)4 * H_ * H_;   // 16,777,216
    const size_t hdr = 4 * H_;                // h-state floats
    const size_t need = hdr * sizeof(float) + (n1i + 3 * nhh) * sizeof(ushort);

    if (ws_size >= need) {
        ushort* W1i = (ushort*)(wsf + hdr);
        ushort* W1h = W1i + n1i;
        ushort* W2i = W1h + nhh;
        ushort* W2h = W2i + nhh;

        hipLaunchKernelGGL(cvt_bf16, dim3(2048), dim3(256), 0, stream,
                           Wih1, W1i, (int)(n1i / 4));
        hipLaunchKernelGGL(cvt_bf16, dim3(2048), dim3(256), 0, stream,
                           Whh1, W1h, (int)(nhh / 4));
        hipLaunchKernelGGL(cvt_bf16, dim3(2048), dim3(256), 0, stream,
                           Wih2, W2i, (int)(nhh / 4));
        hipLaunchKernelGGL(cvt_bf16, dim3(2048), dim3(256), 0, stream,
                           Whh2, W2h, (int)(nhh / 4));

        const ushort* cW1i = W1i; const ushort* cW1h = W1h;
        const ushort* cW2i = W2i; const ushort* cW2h = W2h;
        void* args[] = {
            (void*)&x,
            (void*)&cW1i, (void*)&cW1h, (void*)&cW2i, (void*)&cW2h,
            (void*)&bih1, (void*)&bhh1, (void*)&bih2, (void*)&bhh2,
            (void*)&Wlin, (void*)&blin,
            (void*)&out, (void*)&wsf
        };
        hipLaunchCooperativeKernel((void*)lstm_bf16, dim3(NB), dim3(BSM),
                                   args, 0, stream);
    } else {
        void* args[] = {
            (void*)&x,
            (void*)&Wih1, (void*)&Whh1, (void*)&bih1, (void*)&bhh1,
            (void*)&Wih2, (void*)&Whh2, (void*)&bih2, (void*)&bhh2,
            (void*)&Wlin, (void*)&blin,
            (void*)&out, (void*)&wsf
        };
        hipLaunchCooperativeKernel((void*)lstm_coop, dim3(NB), dim3(BSF),
                                   args, 0, stream);
    }
}

// Round 5
// 45825.861 us; speedup vs baseline: 1.9705x; 1.8929x over previous
//
#include <hip/hip_runtime.h>

#define T_ 1024
#define S_ 1024
#define H_ 2048
#define A_ 128
#define NBLK 256
#define THR 512

typedef __attribute__((ext_vector_type(8))) short short8;
typedef __attribute__((ext_vector_type(4))) float f32x4;

__device__ __forceinline__ float sigmf(float v) { return 1.0f / (1.0f + __expf(-v)); }

__device__ __forceinline__ ushort f2bf(float f) {
    uint u = __float_as_uint(f);
    return (ushort)((u + 0x7fffu + ((u >> 16) & 1u)) >> 16);
}
__device__ __forceinline__ float bflo(uint u) { return __uint_as_float(u << 16); }
__device__ __forceinline__ float bfhi(uint u) { return __uint_as_float(u & 0xffff0000u); }

__device__ __forceinline__ float wave_reduce(float a) {
#pragma unroll
    for (int off = 1; off < 64; off <<= 1) a += __shfl_xor(a, off);
    return a;
}

__device__ __forceinline__ void upk8(uint4 h, float* hv) {
    hv[0] = bflo(h.x); hv[1] = bfhi(h.x);
    hv[2] = bflo(h.y); hv[3] = bfhi(h.y);
    hv[4] = bflo(h.z); hv[5] = bfhi(h.z);
    hv[6] = bflo(h.w); hv[7] = bfhi(h.w);
}
__device__ __forceinline__ void macq(float& a, uint4 w, const float* hv) {
    a = fmaf(bflo(w.x), hv[0], a); a = fmaf(bfhi(w.x), hv[1], a);
    a = fmaf(bflo(w.y), hv[2], a); a = fmaf(bfhi(w.y), hv[3], a);
    a = fmaf(bflo(w.z), hv[4], a); a = fmaf(bfhi(w.z), hv[5], a);
    a = fmaf(bflo(w.w), hv[6], a); a = fmaf(bfhi(w.w), hv[7], a);
}
__device__ __forceinline__ uint4 pack8(const float* __restrict__ s) {
    const float4 f0 = *(const float4*)(s);
    const float4 f1 = *(const float4*)(s + 4);
    uint4 o;
    o.x = (uint)f2bf(f0.x) | ((uint)f2bf(f0.y) << 16);
    o.y = (uint)f2bf(f0.z) | ((uint)f2bf(f0.w) << 16);
    o.z = (uint)f2bf(f1.x) | ((uint)f2bf(f1.y) << 16);
    o.w = (uint)f2bf(f1.z) | ((uint)f2bf(f1.w) << 16);
    return o;
}

// ---------------- fp32 -> bf16 (RNE) packed conversion ----------------
__global__ void cvt_bf16(const float* __restrict__ src,
                         ushort* __restrict__ dst, int n4) {
    int i = blockIdx.x * blockDim.x + threadIdx.x;
    const int stride = gridDim.x * blockDim.x;
    for (; i < n4; i += stride) {
        const uint4 u = reinterpret_cast<const uint4*>(src)[i];
        ushort4 o;
        uint a;
        a = u.x; o.x = (ushort)((a + 0x7fffu + ((a >> 16) & 1u)) >> 16);
        a = u.y; o.y = (ushort)((a + 0x7fffu + ((a >> 16) & 1u)) >> 16);
        a = u.z; o.z = (ushort)((a + 0x7fffu + ((a >> 16) & 1u)) >> 16);
        a = u.w; o.w = (ushort)((a + 0x7fffu + ((a >> 16) & 1u)) >> 16);
        reinterpret_cast<ushort4*>(dst)[i] = o;
    }
}

// ---------------- X1 = x @ W_ih1^T + (b_ih1+b_hh1) : MFMA bf16 GEMM ----------------
__global__ __launch_bounds__(256, 2) void gemm_x1(
    const ushort* __restrict__ Abf, const ushort* __restrict__ Bbf,
    const float* __restrict__ bih1, const float* __restrict__ bhh1,
    float* __restrict__ X1) {
    __shared__ ushort At[64][80];
    __shared__ ushort Bt[64][80];
    const int tx = threadIdx.x;
    const int w = tx >> 6, lane = tx & 63;
    const int row0 = blockIdx.x * 64;
    const int col0 = blockIdx.y * 64;
    f32x4 acc[4];
#pragma unroll
    for (int n4 = 0; n4 < 4; ++n4) { acc[n4][0] = 0.f; acc[n4][1] = 0.f; acc[n4][2] = 0.f; acc[n4][3] = 0.f; }
    const int sr = tx >> 2, sc = (tx & 3) * 16;
    for (int k0 = 0; k0 < 1024; k0 += 64) {
        const uint4 a0 = *(const uint4*)(Abf + (size_t)(row0 + sr) * 1024 + k0 + sc);
        const uint4 a1 = *(const uint4*)(Abf + (size_t)(row0 + sr) * 1024 + k0 + sc + 8);
        const uint4 b0 = *(const uint4*)(Bbf + (size_t)(col0 + sr) * 1024 + k0 + sc);
        const uint4 b1 = *(const uint4*)(Bbf + (size_t)(col0 + sr) * 1024 + k0 + sc + 8);
        __syncthreads();
        *(uint4*)(&At[sr][sc]) = a0;
        *(uint4*)(&At[sr][sc + 8]) = a1;
        *(uint4*)(&Bt[sr][sc]) = b0;
        *(uint4*)(&Bt[sr][sc + 8]) = b1;
        __syncthreads();
#pragma unroll
        for (int kk = 0; kk < 64; kk += 32) {
            short8 af = *(const short8*)(&At[16 * w + (lane & 15)][kk + (lane >> 4) * 8]);
#pragma unroll
            for (int n4 = 0; n4 < 4; ++n4) {
                short8 bf = *(const short8*)(&Bt[n4 * 16 + (lane & 15)][kk + (lane >> 4) * 8]);
                acc[n4] = __builtin_amdgcn_mfma_f32_16x16x32_bf16(af, bf, acc[n4], 0, 0, 0);
            }
        }
    }
#pragma unroll
    for (int n4 = 0; n4 < 4; ++n4) {
        const int col = col0 + n4 * 16 + (lane & 15);
        const float bias = bih1[col] + bhh1[col];
#pragma unroll
        for (int r = 0; r < 4; ++r) {
            const int rowv = row0 + 16 * w + (lane >> 4) * 4 + r;
            X1[(size_t)rowv * 8192 + col] = acc[n4][r] + bias;
        }
    }
}

// ---------------- persistent LSTM: 8 waves/block, 1 h-index/wave ----------------
// Pipelined: iteration t computes L1(t) and L2(t-1); single exchange per iter.
__global__ __launch_bounds__(THR, 2) void lstm_persist(
    const float* __restrict__ X1,
    const float* __restrict__ Whh1,
    const float* __restrict__ W2i, const float* __restrict__ W2h,
    const float* __restrict__ bih2, const float* __restrict__ bhh2,
    const float* __restrict__ Wlin, const float* __restrict__ blin,
    uint* __restrict__ th1, uint* __restrict__ th2,
    float* __restrict__ out)
{
    __shared__ ushort hc[4096];   // h1[t-1] (2048) || h2[t-2] (2048), bf16

    const int b = blockIdx.x, tid = threadIdx.x;
    const int w = tid >> 6, lane = tid & 63;
    const int j = b * 8 + w;      // this wave's h index

    // ---- W_hh1: 4 gate rows of h-index j -> 16 uint4 (64 VGPR) ----
    uint4 w1[16];
#pragma unroll
    for (int g = 0; g < 4; ++g) {
        const float* src = Whh1 + (size_t)(g * H_ + j) * H_;
#pragma unroll
        for (int p = 0; p < 4; ++p)
            w1[g * 4 + p] = pack8(src + p * 512 + lane * 8);
    }

    // ---- [W2i | W2h]: 4 gate rows -> 32 uint4 (128 VGPR) ----
    uint4 w2[32];
#pragma unroll
    for (int g = 0; g < 4; ++g) {
        const float* si = W2i + (size_t)(g * H_ + j) * H_;
        const float* sh = W2h + (size_t)(g * H_ + j) * H_;
#pragma unroll
        for (int p = 0; p < 4; ++p) {
            w2[g * 8 + p]     = pack8(si + p * 512 + lane * 8);
            w2[g * 8 + 4 + p] = pack8(sh + p * 512 + lane * 8);
        }
    }

    float b2g[4];
#pragma unroll
    for (int g = 0; g < 4; ++g) {
        const int R = g * H_ + j;
        b2g[g] = bih2[R] + bhh2[R];
    }

    float c1 = 0.f, c2 = 0.f;   // valid on lane 0

#pragma unroll 1
    for (int t = 0; t <= T_; ++t) {
        // early X1 operand fetch (lane g<4 holds gate g of row j)
        float x1v = 0.f;
        if (t < T_ && lane < 4)
            x1v = X1[(size_t)t * 4 * H_ + lane * H_ + j];

        __syncthreads();   // all waves done reading hc from previous iter

        // ---- stage h1[t-1] (tid<256) and h2[t-2] (tid>=256) into hc ----
        {
            uint gg[8];
            const int half = (tid >> 8);           // 0: h1, 1: h2
            const int base8 = (tid & 255) * 8;
            const int need = half == 0 ? (t >= 1) : (t >= 2);
            if (need) {
                const uint* sp = (half == 0 ? th1 : th2) + ((t - 1) & 1) * H_ + base8;
#pragma unroll
                for (int i = 0; i < 8; ++i)
                    gg[i] = __hip_atomic_load(&sp[i], __ATOMIC_RELAXED, __HIP_MEMORY_SCOPE_AGENT);
#pragma unroll
                for (int i = 0; i < 8; ++i)
                    while ((gg[i] >> 16) != (uint)(t - 1)) {
                        __builtin_amdgcn_s_sleep(1);
                        gg[i] = __hip_atomic_load(&sp[i], __ATOMIC_RELAXED, __HIP_MEMORY_SCOPE_AGENT);
                    }
            } else {
#pragma unroll
                for (int i = 0; i < 8; ++i) gg[i] = 0u;
            }
            uint4 o;
            o.x = (gg[0] & 0xffffu) | (gg[1] << 16);
            o.y = (gg[2] & 0xffffu) | (gg[3] << 16);
            o.z = (gg[4] & 0xffffu) | (gg[5] << 16);
            o.w = (gg[6] & 0xffffu) | (gg[7] << 16);
            *(uint4*)(hc + half * 2048 + base8) = o;
        }
        __syncthreads();

        // ---- L1(t): h1[t] = cell1(x[t], h1[t-1]) ----
        if (t < T_) {
            float s[4] = {0.f, 0.f, 0.f, 0.f};
#pragma unroll
            for (int p = 0; p < 4; ++p) {
                const uint4 hq = *(const uint4*)(hc + p * 512 + lane * 8);
                float hv[8]; upk8(hq, hv);
#pragma unroll
                for (int g = 0; g < 4; ++g) macq(s[g], w1[g * 4 + p], hv);
            }
#pragma unroll
            for (int g = 0; g < 4; ++g) s[g] = wave_reduce(s[g]);
            const float x0 = __shfl(x1v, 0), x1s = __shfl(x1v, 1);
            const float x2 = __shfl(x1v, 2), x3 = __shfl(x1v, 3);
            if (lane == 0) {
                const float ig = sigmf(s[0] + x0);
                const float fg = sigmf(s[1] + x1s);
                const float gv = tanhf(s[2] + x2);
                const float og = sigmf(s[3] + x3);
                c1 = fg * c1 + ig * gv;
                const float h1n = og * tanhf(c1);
                const uint pv = ((uint)t << 16) | (uint)f2bf(h1n);
                __hip_atomic_store(&th1[(t & 1) * H_ + j], pv,
                                   __ATOMIC_RELAXED, __HIP_MEMORY_SCOPE_AGENT);
            }
        }

        // ---- L2(t-1): h2[t-1] = cell2(h1[t-1], h2[t-2]) ----
        if (t >= 1) {
            float s2[4] = {0.f, 0.f, 0.f, 0.f};
#pragma unroll
            for (int p = 0; p < 8; ++p) {
                const uint4 hq = *(const uint4*)(hc + p * 512 + lane * 8);
                float hv[8]; upk8(hq, hv);
#pragma unroll
                for (int g = 0; g < 4; ++g) macq(s2[g], w2[g * 8 + p], hv);
            }
#pragma unroll
            for (int g = 0; g < 4; ++g) s2[g] = wave_reduce(s2[g]);
            if (lane == 0) {
                const float ig = sigmf(s2[0] + b2g[0]);
                const float fg = sigmf(s2[1] + b2g[1]);
                const float gv = tanhf(s2[2] + b2g[2]);
                const float og = sigmf(s2[3] + b2g[3]);
                c2 = fg * c2 + ig * gv;
                const float h2n = og * tanhf(c2);
                const uint pv = ((uint)t << 16) | (uint)f2bf(h2n);
                __hip_atomic_store(&th2[(t & 1) * H_ + j], pv,
                                   __ATOMIC_RELAXED, __HIP_MEMORY_SCOPE_AGENT);
            }
        }
    }

    // ---- linear head on h2[T-1] (published at iter T_, slot 0, tag T_) ----
    if (b < 16) {
        __syncthreads();
        if (tid < 256) {
            const uint* sp = th2 + (T_ & 1) * H_ + tid * 8;
            uint gg[8];
#pragma unroll
            for (int i = 0; i < 8; ++i) {
                gg[i] = __hip_atomic_load(&sp[i], __ATOMIC_RELAXED, __HIP_MEMORY_SCOPE_AGENT);
                while ((gg[i] >> 16) != (uint)T_) {
                    __builtin_amdgcn_s_sleep(1);
                    gg[i] = __hip_atomic_load(&sp[i], __ATOMIC_RELAXED, __HIP_MEMORY_SCOPE_AGENT);
                }
            }
            uint4 o;
            o.x = (gg[0] & 0xffffu) | (gg[1] << 16);
            o.y = (gg[2] & 0xffffu) | (gg[3] << 16);
            o.z = (gg[4] & 0xffffu) | (gg[5] << 16);
            o.w = (gg[6] & 0xffffu) | (gg[7] << 16);
            *(uint4*)(hc + tid * 8) = o;
        }
        __syncthreads();
        const int r = b * 8 + w;
        const float* wrow = Wlin + (size_t)r * H_;
        float a = 0.f;
#pragma unroll
        for (int p = 0; p < 4; ++p) {
            const uint4 hq = *(const uint4*)(hc + p * 512 + lane * 8);
            float hv[8]; upk8(hq, hv);
            const float4 w0 = *(const float4*)(wrow + p * 512 + lane * 8);
            const float4 w1v = *(const float4*)(wrow + p * 512 + lane * 8 + 4);
            a = fmaf(w0.x, hv[0], a); a = fmaf(w0.y, hv[1], a);
            a = fmaf(w0.z, hv[2], a); a = fmaf(w0.w, hv[3], a);
            a = fmaf(w1v.x, hv[4], a); a = fmaf(w1v.y, hv[5], a);
            a = fmaf(w1v.z, hv[6], a); a = fmaf(w1v.w, hv[7], a);
        }
        a = wave_reduce(a);
        if (lane == 0) out[r] = a + blin[r];
    }
}

extern "C" void kernel_launch(void* const* d_in, const int* in_sizes, int n_in,
                              void* d_out, int out_size, void* d_ws, size_t ws_size,
                              hipStream_t stream) {
    const float* x    = (const float*)d_in[0];
    const float* Wih1 = (const float*)d_in[1];
    const float* Whh1 = (const float*)d_in[2];
    const float* bih1 = (const float*)d_in[3];
    const float* bhh1 = (const float*)d_in[4];
    const float* Wih2 = (const float*)d_in[5];
    const float* Whh2 = (const float*)d_in[6];
    const float* bih2 = (const float*)d_in[7];
    const float* bhh2 = (const float*)d_in[8];
    const float* Wlin = (const float*)d_in[9];
    const float* blin = (const float*)d_in[10];
    float* out = (float*)d_out;

    // ws layout (bytes):
    // [0, 33554432)          X1   [1024][8192] f32
    // [33554432, 35651584)   x_bf16 [1024][1024]
    // [35651584, 52428800)   W1i_bf16 [8192][1024]
    // [52428800, 52445184)   th1  [2][2048] u32 (tagged h1)
    // [52445184, 52461568)   th2  [2][2048] u32 (tagged h2)
    float*  X1    = (float*)d_ws;
    ushort* xbf   = (ushort*)((char*)d_ws + 33554432);
    ushort* w1ibf = (ushort*)((char*)d_ws + 35651584);
    uint*   th1   = (uint*)((char*)d_ws + 52428800);
    uint*   th2   = (uint*)((char*)d_ws + 52445184);

    hipLaunchKernelGGL(cvt_bf16, dim3(512), dim3(256), 0, stream, x, xbf, 262144);
    hipLaunchKernelGGL(cvt_bf16, dim3(2048), dim3(256), 0, stream, Wih1, w1ibf, 2097152);
    hipLaunchKernelGGL(gemm_x1, dim3(16, 128), dim3(256), 0, stream,
                       (const ushort*)xbf, (const ushort*)w1ibf, bih1, bhh1, X1);
    hipMemsetAsync((void*)th1, 0xFF, 32768, stream);

    const float* aX1 = X1;
    uint* ath1 = th1; uint* ath2 = th2;
    void* args[] = {
        (void*)&aX1, (void*)&Whh1, (void*)&Wih2, (void*)&Whh2,
        (void*)&bih2, (void*)&bhh2, (void*)&Wlin, (void*)&blin,
        (void*)&ath1, (void*)&ath2, (void*)&out
    };

    int maxb = 0;
    hipError_t oe = hipOccupancyMaxActiveBlocksPerMultiprocessor(
        &maxb, (const void*)lstm_persist, THR, 0);
    if (oe == hipSuccess && maxb >= 1) {
        hipLaunchCooperativeKernel((void*)lstm_persist, dim3(NBLK), dim3(THR),
                                   args, 0, stream);
    } else {
        hipLaunchKernelGGL(lstm_persist, dim3(NBLK), dim3(THR), 0, stream,
                           aX1, Whh1, Wih2, Whh2, bih2, bhh2, Wlin, blin,
                           ath1, ath2, out);
    }
}